// Round 7
// baseline (1244.304 us; speedup 1.0000x reference)
//
#include <hip/hip_runtime.h>

// SINGLE fused mega-kernel v2: one 64-token window per 1024-thread block (16 waves).
//   x -> GEMM1+LN+GELU -> h(LDS) -> G2a(V)+G2b(QK) -> window attn -> ao(LDS)
//     -> GEMM3+LN+GELU -> h2(LDS) -> GEMM4 -> out (f32 global)
// Round-6 mega spilled ~600 MB scratch (register peak > 128 with 16-wave blocks).
// v2 anti-spill: (a) V-round split from QK-round (peak acc 48->32, vreg dies
// immediately into vt), (b) sched_barrier(0) before G3/G4 so their weight loads
// aren't hoisted into the attention live-range, (c) G4 reshaped to 32x32 wave
// tiles (halves its LDS reads).
// LDS (128 KB):
//   [0,64K)    rA/rB: x-tile -> h -> (after S2) qk slots -> (after S5) h2
//   [64K,96K)  vt 8 heads x 4K (staged right after V-round; part overlays
//              [64K,72K) during G1/G3 gemmT only)
//   [96K,128K) aoS: attention output tile (written by attn, read by G3)

typedef __bf16 bf16_t;
typedef __bf16 bf16x8 __attribute__((ext_vector_type(8)));
typedef __bf16 bf16x4 __attribute__((ext_vector_type(4)));
typedef float f32x4 __attribute__((ext_vector_type(4)));

__device__ __forceinline__ f32x4 mfma16(bf16x8 a, bf16x8 b, f32x4 acc) {
  return __builtin_amdgcn_mfma_f32_16x16x32_bf16(a, b, acc, 0, 0, 0);
}

// XOR-swizzle: fold row's low 3 bits into byte-address bits [6:4].
#define SWZ(row, byteoff) ((byteoff) ^ (((row) & 7) << 4))

// cheap GELU: tanh form, max |err| vs exact erf-GELU ~3e-4.
__device__ __forceinline__ float gelu_f(float v) {
  float e = __expf(v * (1.59576912f + 0.07135482f * v * v));
  return v - v * __builtin_amdgcn_rcpf(1.0f + e);
}

// transpose + convert: dst[n*K + k] = bf16(src[k*N + n])
__global__ void wtrans_kernel(const float* __restrict__ src, bf16_t* __restrict__ dst,
                              int kshift, int N, int total) {
  int i = blockIdx.x * 256 + threadIdx.x;
  if (i >= total) return;
  int K = 1 << kshift;
  int k = i & (K - 1);
  int n = i >> kshift;
  dst[i] = (bf16_t)src[(size_t)k * N + n];
}

// expand rpb[(2*8-1)^2][8] -> bt[8][64][64] f32 (window-invariant)
__global__ void biastab_kernel(const float* __restrict__ rpb, float* __restrict__ bt) {
  int e = blockIdx.x * 256 + threadIdx.x;  // 32768 total
  int hd = e >> 12, i = (e >> 6) & 63, j = e & 63;
  int idx = ((i >> 3) - (j >> 3) + 7) * 15 + ((i & 7) - (j & 7) + 7);
  bt[e] = rpb[idx * 8 + hd];
}

// 16-wave transposed GEMM (C^T = W * A^T) + bias + LayerNorm(512) + cheap GELU.
// Each wave produces 32 output features. bsrc: [64 tok][256 k] bf16 LDS tile
// (swizzled, 512 B rows). wt: [512 feat][256 k] bf16 global.
// Output staged to h-halves in LDS. Contains ONE __syncthreads.
__device__ __forceinline__ void gemmT_ln_gelu16(
    const char* bsrc, const bf16_t* __restrict__ wt,
    const float* __restrict__ bias, const float* __restrict__ gamma,
    const float* __restrict__ beta,
    char* dst, int flb, float2* part, int wave, int g, int c)
{
  f32x4 acc[2][4] = {};
#pragma unroll
  for (int kt = 0; kt < 8; ++kt) {
    bf16x8 a[2], b[4];
#pragma unroll
    for (int mt = 0; mt < 2; ++mt)
      a[mt] = *(const bf16x8*)(wt + (size_t)(wave * 32 + mt * 16 + c) * 256 + kt * 32 + g * 8);
#pragma unroll
    for (int nt = 0; nt < 4; ++nt) {
      int T = nt * 16 + c;
      b[nt] = *(const bf16x8*)(bsrc + SWZ(T, T * 512 + kt * 64 + g * 16));
    }
#pragma unroll
    for (int mt = 0; mt < 2; ++mt)
#pragma unroll
      for (int nt = 0; nt < 4; ++nt)
        acc[mt][nt] = mfma16(a[mt], b[nt], acc[mt][nt]);
  }
  float s[4] = {0.f, 0.f, 0.f, 0.f}, ss[4] = {0.f, 0.f, 0.f, 0.f};
#pragma unroll
  for (int mt = 0; mt < 2; ++mt) {
    float4 b4 = *(const float4*)(bias + wave * 32 + mt * 16 + g * 4);
#pragma unroll
    for (int nt = 0; nt < 4; ++nt)
#pragma unroll
      for (int r = 0; r < 4; ++r) {
        float v = acc[mt][nt][r] + ((const float*)&b4)[r];
        acc[mt][nt][r] = v;
        s[nt] += v;
        ss[nt] += v * v;
      }
  }
#pragma unroll
  for (int nt = 0; nt < 4; ++nt) {
    float sv = s[nt], ssv = ss[nt];
    sv += __shfl_xor(sv, 16, 64); ssv += __shfl_xor(ssv, 16, 64);
    sv += __shfl_xor(sv, 32, 64); ssv += __shfl_xor(ssv, 32, 64);
    if (g == 0) part[wave * 64 + nt * 16 + c] = make_float2(sv, ssv);
  }
  __syncthreads();
#pragma unroll
  for (int nt = 0; nt < 4; ++nt) {
    float sv = 0.f, ssv = 0.f;
#pragma unroll
    for (int w = 0; w < 16; ++w) {
      float2 p2 = part[w * 64 + nt * 16 + c];
      sv += p2.x; ssv += p2.y;
    }
    float m = sv * (1.f / 512.f);
    float rstd = rsqrtf(ssv * (1.f / 512.f) - m * m + 1e-5f);
#pragma unroll
    for (int mt = 0; mt < 2; ++mt)
#pragma unroll
      for (int r = 0; r < 4; ++r)
        acc[mt][nt][r] = (acc[mt][nt][r] - m) * rstd;
  }
#pragma unroll
  for (int mt = 0; mt < 2; ++mt) {
    float4 g4 = *(const float4*)(gamma + wave * 32 + mt * 16 + g * 4);
    float4 be4 = *(const float4*)(beta + wave * 32 + mt * 16 + g * 4);
    int f0 = flb + mt * 16 + g * 4;
#pragma unroll
    for (int nt = 0; nt < 4; ++nt) {
      int T = nt * 16 + c;
      bf16x4 h4;
#pragma unroll
      for (int r = 0; r < 4; ++r) {
        float v = acc[mt][nt][r] * ((const float*)&g4)[r] + ((const float*)&be4)[r];
        h4[r] = (bf16_t)gelu_f(v);
      }
      *(bf16x4*)(dst + SWZ(T, T * 512 + f0 * 2)) = h4;
    }
  }
}

// ========================= fused mega-kernel v2 =========================
__global__ __launch_bounds__(1024, 1) void mega_kernel(
    const float* __restrict__ x,
    const bf16_t* __restrict__ w1t, const float* __restrict__ b1,
    const float* __restrict__ gamma1, const float* __restrict__ beta1,
    const bf16_t* __restrict__ w2t, const float* __restrict__ b2,
    const float* __restrict__ bt,
    const bf16_t* __restrict__ wp1t, const float* __restrict__ bp1,
    const float* __restrict__ gp, const float* __restrict__ bep,
    const bf16_t* __restrict__ wp2t, const float* __restrict__ bp2,
    float* __restrict__ out)
{
  __shared__ __align__(16) char sm[131072];
  char* rA = sm;
  char* rB = sm + 32768;
  float2* part = (float2*)(sm + 65536);  // overlays vt region; dead before vt staged
  char* aoS = sm + 98304;                // [96K,128K)
  const int tid = threadIdx.x;
  const int wave = tid >> 6, lane = tid & 63;
  const int g = lane >> 4, c = lane & 15;
  const int win = blockIdx.x;

  // ---- stage x (f32 -> bf16 tile, coalesced) ----
  const float* xw = x + (size_t)win * 16384;
#pragma unroll
  for (int it = 0; it < 4; ++it) {
    int e = it * 4096 + tid * 4;
    float4 v = *(const float4*)(xw + e);
    int row = e >> 8, col = e & 255;
    bf16x4 t4;
    t4[0] = (bf16_t)v.x; t4[1] = (bf16_t)v.y; t4[2] = (bf16_t)v.z; t4[3] = (bf16_t)v.w;
    *(bf16x4*)(rA + SWZ(row, row * 512 + col * 2)) = t4;
  }
  __syncthreads();
  gemmT_ln_gelu16(rA, w1t, b1, gamma1, beta1, (wave < 8) ? rB : rA, (wave & 7) * 32,
                  part, wave, g, c);
  __syncthreads();  // S1: h complete (rB = feats 0-255, rA = feats 256-511); part dead

  const int hh = wave >> 1, mh = wave & 1;

  // ---- G2a: V round (acc 16 regs); stage vt immediately (disjoint region,
  //      no barrier needed; overlaps following QK round) ----
  {
    f32x4 accv[4] = {};
    const bf16_t* wv = w2t + (size_t)(512 + hh * 32 + mh * 16 + c) * 512;
#pragma unroll
    for (int kt = 0; kt < 16; ++kt) {
      const char* hb = (kt < 8) ? rB : rA;
      const int ko = (kt & 7) * 64 + g * 16;
      bf16x8 av = *(const bf16x8*)(wv + kt * 32 + g * 8);
      bf16x8 b[4];
#pragma unroll
      for (int nt = 0; nt < 4; ++nt) {
        int T = nt * 16 + c;
        b[nt] = *(const bf16x8*)(hb + SWZ(T, T * 512 + ko));
      }
#pragma unroll
      for (int nt = 0; nt < 4; ++nt)
        accv[nt] = mfma16(av, b[nt], accv[nt]);
    }
    float4 bv4 = *(const float4*)(b2 + 512 + hh * 32 + mh * 16 + g * 4);
    char* vs = sm + 65536 + hh * 4096;
    const int d0 = mh * 16 + g * 4;
#pragma unroll
    for (int nt = 0; nt < 4; ++nt) {
      int T = nt * 16 + c;
#pragma unroll
      for (int r = 0; r < 4; ++r) {
        int d = d0 + r;
        *(bf16_t*)(vs + SWZ(d, d * 128 + T * 2)) =
            (bf16_t)(accv[nt][r] + ((const float*)&bv4)[r]);
      }
    }
  }

  // ---- G2b: Q,K fused round (acc 32 regs) ----
  bf16x4 qreg[4], kreg[4];
  {
    f32x4 accq[4] = {}, acck[4] = {};
    const bf16_t* wq = w2t + (size_t)(hh * 32 + mh * 16 + c) * 512;
    const bf16_t* wk = wq + (size_t)256 * 512;
#pragma unroll
    for (int kt = 0; kt < 16; ++kt) {
      const char* hb = (kt < 8) ? rB : rA;
      const int ko = (kt & 7) * 64 + g * 16;
      bf16x8 aq = *(const bf16x8*)(wq + kt * 32 + g * 8);
      bf16x8 ak = *(const bf16x8*)(wk + kt * 32 + g * 8);
      bf16x8 b[4];
#pragma unroll
      for (int nt = 0; nt < 4; ++nt) {
        int T = nt * 16 + c;
        b[nt] = *(const bf16x8*)(hb + SWZ(T, T * 512 + ko));
      }
#pragma unroll
      for (int nt = 0; nt < 4; ++nt) {
        accq[nt] = mfma16(aq, b[nt], accq[nt]);
        acck[nt] = mfma16(ak, b[nt], acck[nt]);
      }
    }
    float4 bq4 = *(const float4*)(b2 + hh * 32 + mh * 16 + g * 4);
    float4 bk4 = *(const float4*)(b2 + 256 + hh * 32 + mh * 16 + g * 4);
#pragma unroll
    for (int nt = 0; nt < 4; ++nt)
#pragma unroll
      for (int r = 0; r < 4; ++r) {
        qreg[nt][r] = (bf16_t)((accq[nt][r] + ((const float*)&bq4)[r]) * 0.17677669529663687f);
        kreg[nt][r] = (bf16_t)(acck[nt][r] + ((const float*)&bk4)[r]);
      }
  }
  __syncthreads();  // S2: all h reads done -> [0,64K) reusable

  // ---- stage q,k (all 8 heads into [0,64K)) ----
  {
    char* qb = sm + hh * 8192;
    const int d0 = mh * 16 + g * 4;
#pragma unroll
    for (int nt = 0; nt < 4; ++nt) {
      int T = nt * 16 + c;
      *(bf16x4*)(qb + SWZ(T, T * 64 + d0 * 2)) = qreg[nt];
      *(bf16x4*)(qb + 4096 + SWZ(T, T * 64 + d0 * 2)) = kreg[nt];
    }
  }
  __syncthreads();  // S3: q/k/vt visible

  // ---- attention: 16 waves = 8 heads x 2 row-halves, single pass ----
  {
    const int h8 = wave & 7, rowbase = (wave >> 3) * 32;
    char* qb = sm + h8 * 8192;
    char* vslot = sm + 65536 + h8 * 4096;
    const float* btab = bt + h8 * 4096;  // [64][64] f32

    bf16x8 aq[2], bk[4];
#pragma unroll
    for (int mt = 0; mt < 2; ++mt) {
      int t = rowbase + mt * 16 + c;
      aq[mt] = *(const bf16x8*)(qb + SWZ(t, t * 64 + g * 16));
    }
#pragma unroll
    for (int nt = 0; nt < 4; ++nt) {
      int t = nt * 16 + c;
      bk[nt] = *(const bf16x8*)(qb + 4096 + SWZ(t, t * 64 + g * 16));
    }
    float p[2][4][4];
#pragma unroll
    for (int mt = 0; mt < 2; ++mt)
#pragma unroll
      for (int nt = 0; nt < 4; ++nt) {
        f32x4 z = {0.f, 0.f, 0.f, 0.f};
        f32x4 s4 = mfma16(aq[mt], bk[nt], z);
#pragma unroll
        for (int r = 0; r < 4; ++r) {
          int i = rowbase + mt * 16 + g * 4 + r, j = nt * 16 + c;
          p[mt][nt][r] = s4[r] + btab[i * 64 + j];
        }
      }
#pragma unroll
    for (int mt = 0; mt < 2; ++mt)
#pragma unroll
      for (int r = 0; r < 4; ++r) {
        float mx = fmaxf(fmaxf(p[mt][0][r], p[mt][1][r]), fmaxf(p[mt][2][r], p[mt][3][r]));
#pragma unroll
        for (int m = 1; m < 16; m <<= 1) mx = fmaxf(mx, __shfl_xor(mx, m, 64));
        float sum = 0.f;
#pragma unroll
        for (int nt = 0; nt < 4; ++nt) {
          float e = __expf(p[mt][nt][r] - mx);
          p[mt][nt][r] = e; sum += e;
        }
#pragma unroll
        for (int m = 1; m < 16; m <<= 1) sum += __shfl_xor(sum, m, 64);
        float rinv = 1.f / sum;
#pragma unroll
        for (int nt = 0; nt < 4; ++nt) p[mt][nt][r] *= rinv;
      }
    __syncthreads();  // S4: all q/k reads done before P overlays qk slots

#pragma unroll
    for (int mt = 0; mt < 2; ++mt)
#pragma unroll
      for (int nt = 0; nt < 4; ++nt)
#pragma unroll
        for (int r = 0; r < 4; ++r) {
          int i = rowbase + mt * 16 + g * 4 + r, j = nt * 16 + c;
          *(bf16_t*)(qb + SWZ(i, i * 128 + j * 2)) = (bf16_t)p[mt][nt][r];
        }
    asm volatile("s_waitcnt lgkmcnt(0)" ::: "memory");  // in-wave P write->read (own rows only)
    f32x4 oacc[2][2] = {};
#pragma unroll
    for (int kp = 0; kp < 2; ++kp) {
      bf16x8 ap[2], bv[2];
#pragma unroll
      for (int mt = 0; mt < 2; ++mt) {
        int t = rowbase + mt * 16 + c;
        ap[mt] = *(const bf16x8*)(qb + SWZ(t, t * 128 + kp * 64 + g * 16));
      }
#pragma unroll
      for (int nt = 0; nt < 2; ++nt) {
        int d = nt * 16 + c;
        bv[nt] = *(const bf16x8*)(vslot + SWZ(d, d * 128 + kp * 64 + g * 16));
      }
#pragma unroll
      for (int mt = 0; mt < 2; ++mt)
#pragma unroll
        for (int nt = 0; nt < 2; ++nt)
          oacc[mt][nt] = mfma16(ap[mt], bv[nt], oacc[mt][nt]);
    }
    // ---- ao stays in LDS (aoS), [64 tok][256 feat] swizzled 512B rows ----
#pragma unroll
    for (int mt = 0; mt < 2; ++mt)
#pragma unroll
      for (int nt = 0; nt < 2; ++nt)
#pragma unroll
        for (int r = 0; r < 4; ++r) {
          int T = rowbase + mt * 16 + g * 4 + r;
          int f = h8 * 32 + nt * 16 + c;
          *(bf16_t*)(aoS + SWZ(T, T * 512 + f * 2)) = (bf16_t)oacc[mt][nt][r];
        }
  }
  __syncthreads();  // S5: aoS complete; qk/vt dead -> rA/rB + part reusable

  // keep G3/G4 weight loads out of the attention live-range
  __builtin_amdgcn_sched_barrier(0);

  // ---- G3: ao -> GEMM3+LN+GELU -> h2 (rA/rB) ----
  gemmT_ln_gelu16(aoS, wp1t, bp1, gp, bep, (wave < 8) ? rB : rA, (wave & 7) * 32,
                  part, wave, g, c);
  __syncthreads();  // S6: h2 complete (rB = feats 0-255, rA = feats 256-511)

  __builtin_amdgcn_sched_barrier(0);

  // ---- GEMM4: out = h2 @ wp2 + bp2 (16 waves = 8 feat-32s x 2 token-32s) ----
  {
    const int f0 = (wave & 7) * 32, t0 = (wave >> 3) * 32;
    f32x4 acc[2][2] = {};
#pragma unroll
    for (int kt = 0; kt < 16; ++kt) {
      const char* hb = (kt < 8) ? rB : rA;
      const int ko = (kt & 7) * 64 + g * 16;
      bf16x8 a[2], b[2];
#pragma unroll
      for (int mt = 0; mt < 2; ++mt)
        a[mt] = *(const bf16x8*)(wp2t + (size_t)(f0 + mt * 16 + c) * 512 + kt * 32 + g * 8);
#pragma unroll
      for (int nt = 0; nt < 2; ++nt) {
        int T = t0 + nt * 16 + c;
        b[nt] = *(const bf16x8*)(hb + SWZ(T, T * 512 + ko));
      }
#pragma unroll
      for (int mt = 0; mt < 2; ++mt)
#pragma unroll
        for (int nt = 0; nt < 2; ++nt)
          acc[mt][nt] = mfma16(a[mt], b[nt], acc[mt][nt]);
    }
    float* ow = out + (size_t)win * 16384;
#pragma unroll
    for (int mt = 0; mt < 2; ++mt) {
      float4 b4 = *(const float4*)(bp2 + f0 + mt * 16 + g * 4);
#pragma unroll
      for (int nt = 0; nt < 2; ++nt) {
        int T = t0 + nt * 16 + c;
        f32x4 o4;
#pragma unroll
        for (int r = 0; r < 4; ++r) o4[r] = acc[mt][nt][r] + ((const float*)&b4)[r];
        *(f32x4*)(ow + T * 256 + f0 + mt * 16 + g * 4) = o4;
      }
    }
  }
}

extern "C" void kernel_launch(void* const* d_in, const int* in_sizes, int n_in,
                              void* d_out, int out_size, void* d_ws, size_t ws_size,
                              hipStream_t stream) {
  const float* x   = (const float*)d_in[0];
  const float* w1  = (const float*)d_in[1];
  const float* b1  = (const float*)d_in[2];
  const float* g1  = (const float*)d_in[3];
  const float* be1 = (const float*)d_in[4];
  const float* w2  = (const float*)d_in[5];
  const float* b2  = (const float*)d_in[6];
  const float* rpb = (const float*)d_in[7];
  const float* wp1 = (const float*)d_in[8];
  const float* bp1 = (const float*)d_in[9];
  const float* gp  = (const float*)d_in[10];
  const float* bep = (const float*)d_in[11];
  const float* wp2 = (const float*)d_in[12];
  const float* bp2 = (const float*)d_in[13];
  float* out = (float*)d_out;
  char* ws = (char*)d_ws;
  // ws layout: transposed bf16 weights (1.5 MB) | bias table (128 KB)
  bf16_t* w1t  = (bf16_t*)(ws + 0);          // [512][256]
  bf16_t* w2t  = (bf16_t*)(ws + 262144);     // [768][512]
  bf16_t* wp1t = (bf16_t*)(ws + 1048576);    // [512][256]
  bf16_t* wp2t = (bf16_t*)(ws + 1310720);    // [256][512]
  float*  bt   = (float*)(ws + 1572864);     // [8][64][64] f32

  wtrans_kernel<<<512, 256, 0, stream>>>(w1, w1t, 8, 512, 131072);
  wtrans_kernel<<<1536, 256, 0, stream>>>(w2, w2t, 9, 768, 393216);
  wtrans_kernel<<<512, 256, 0, stream>>>(wp1, wp1t, 8, 512, 131072);
  wtrans_kernel<<<512, 256, 0, stream>>>(wp2, wp2t, 9, 256, 131072);
  biastab_kernel<<<128, 256, 0, stream>>>(rpb, bt);

  mega_kernel<<<4096, 1024, 0, stream>>>(x, w1t, b1, g1, be1, w2t, b2, bt,
                                         wp1t, bp1, gp, bep, wp2t, bp2, out);
}

// Round 8
// 1209.112 us; speedup vs baseline: 1.0291x; 1.0291x over previous
//
#include <hip/hip_runtime.h>

// Two-kernel pipeline (round-5 structure = best measured), one 64-token window
// per 1024-thread block (16 waves).
//   K_A: x -> GEMM1+LN+GELU -> h(LDS) -> fused GEMM2(qkv, ONE pass, direct
//        LDS store) -> window attn -> ao (bf16 global)
//   K_B: ao -> GEMM3+LN+GELU -> h2(LDS) -> GEMM4(32x32 tiles) -> out (f32)
// K_A LDS (160 KB = full CU pool; 1 block/CU which is the measured residency
// anyway at this register footprint):
//   [0,64K)     rA/rB: x-tile -> h halves
//   [64K,128K)  qk slots, 8 heads x 8K (q | k at +4K); written DIRECTLY by G2
//               (no reg-hold / re-stage phase / extra barrier); P overlays own
//               head's q area during PV. LN partials overlay [64K,72K) during
//               gemmT (dead before G2 writes).
//   [128K,160K) vt 8 heads x 4K, written directly by G2.
// Register model (unified VGPR/AGPR on gfx950): reported VGPR_Count excludes
// acc; arch64 + acc48 => 4 waves/SIMD bucket. 16-wave block = full residency.

typedef __bf16 bf16_t;
typedef __bf16 bf16x8 __attribute__((ext_vector_type(8)));
typedef __bf16 bf16x4 __attribute__((ext_vector_type(4)));
typedef float f32x4 __attribute__((ext_vector_type(4)));

__device__ __forceinline__ f32x4 mfma16(bf16x8 a, bf16x8 b, f32x4 acc) {
  return __builtin_amdgcn_mfma_f32_16x16x32_bf16(a, b, acc, 0, 0, 0);
}

// XOR-swizzle: fold row's low 3 bits into byte-address bits [6:4].
#define SWZ(row, byteoff) ((byteoff) ^ (((row) & 7) << 4))

// cheap GELU: tanh form, max |err| vs exact erf-GELU ~3e-4.
__device__ __forceinline__ float gelu_f(float v) {
  float e = __expf(v * (1.59576912f + 0.07135482f * v * v));
  return v - v * __builtin_amdgcn_rcpf(1.0f + e);
}

// fused prologue: all 4 weight transposes + bias-table expansion in ONE launch.
// segments: w1t[131072] | w2t[393216] | wp1t[131072] | wp2t[131072] | bt[32768]
__global__ void prep_kernel(const float* __restrict__ w1, const float* __restrict__ w2,
                            const float* __restrict__ wp1, const float* __restrict__ wp2,
                            const float* __restrict__ rpb,
                            bf16_t* __restrict__ w1t, bf16_t* __restrict__ w2t,
                            bf16_t* __restrict__ wp1t, bf16_t* __restrict__ wp2t,
                            float* __restrict__ bt) {
  int i = blockIdx.x * 256 + threadIdx.x;
  if (i < 131072) {                    // w1t: [512 feat][256 k], w1 is [256][512]
    int k = i & 255, n = i >> 8;
    w1t[i] = (bf16_t)w1[k * 512 + n];
    return;
  }
  i -= 131072;
  if (i < 393216) {                    // w2t: [768 feat][512 k], w2 is [512][768]
    int k = i & 511, n = i >> 9;
    w2t[i] = (bf16_t)w2[k * 768 + n];
    return;
  }
  i -= 393216;
  if (i < 131072) {                    // wp1t: [512 feat][256 k], wp1 is [256][512]
    int k = i & 255, n = i >> 8;
    wp1t[i] = (bf16_t)wp1[k * 512 + n];
    return;
  }
  i -= 131072;
  if (i < 131072) {                    // wp2t: [256 feat][512 k], wp2 is [512][256]
    int k = i & 511, n = i >> 9;
    wp2t[i] = (bf16_t)wp2[k * 256 + n];
    return;
  }
  i -= 131072;
  if (i < 32768) {                     // bt[8][64][64]
    int hd = i >> 12, r = (i >> 6) & 63, j = i & 63;
    int idx = ((r >> 3) - (j >> 3) + 7) * 15 + ((r & 7) - (j & 7) + 7);
    bt[i] = rpb[idx * 8 + hd];
  }
}

// 16-wave transposed GEMM (C^T = W * A^T) + bias + LayerNorm(512) + cheap GELU.
// Each wave produces 32 output features. bsrc: [64 tok][256 k] bf16 LDS tile
// (swizzled, 512 B rows). wt: [512 feat][256 k] bf16 global.
// Output staged to h-halves in LDS. Contains ONE __syncthreads.
__device__ __forceinline__ void gemmT_ln_gelu16(
    const char* bsrc, const bf16_t* __restrict__ wt,
    const float* __restrict__ bias, const float* __restrict__ gamma,
    const float* __restrict__ beta,
    char* dst, int flb, float2* part, int wave, int g, int c)
{
  f32x4 acc[2][4] = {};
#pragma unroll
  for (int kt = 0; kt < 8; ++kt) {
    bf16x8 a[2], b[4];
#pragma unroll
    for (int mt = 0; mt < 2; ++mt)
      a[mt] = *(const bf16x8*)(wt + (size_t)(wave * 32 + mt * 16 + c) * 256 + kt * 32 + g * 8);
#pragma unroll
    for (int nt = 0; nt < 4; ++nt) {
      int T = nt * 16 + c;
      b[nt] = *(const bf16x8*)(bsrc + SWZ(T, T * 512 + kt * 64 + g * 16));
    }
#pragma unroll
    for (int mt = 0; mt < 2; ++mt)
#pragma unroll
      for (int nt = 0; nt < 4; ++nt)
        acc[mt][nt] = mfma16(a[mt], b[nt], acc[mt][nt]);
  }
  float s[4] = {0.f, 0.f, 0.f, 0.f}, ss[4] = {0.f, 0.f, 0.f, 0.f};
#pragma unroll
  for (int mt = 0; mt < 2; ++mt) {
    float4 b4 = *(const float4*)(bias + wave * 32 + mt * 16 + g * 4);
#pragma unroll
    for (int nt = 0; nt < 4; ++nt)
#pragma unroll
      for (int r = 0; r < 4; ++r) {
        float v = acc[mt][nt][r] + ((const float*)&b4)[r];
        acc[mt][nt][r] = v;
        s[nt] += v;
        ss[nt] += v * v;
      }
  }
#pragma unroll
  for (int nt = 0; nt < 4; ++nt) {
    float sv = s[nt], ssv = ss[nt];
    sv += __shfl_xor(sv, 16, 64); ssv += __shfl_xor(ssv, 16, 64);
    sv += __shfl_xor(sv, 32, 64); ssv += __shfl_xor(ssv, 32, 64);
    if (g == 0) part[wave * 64 + nt * 16 + c] = make_float2(sv, ssv);
  }
  __syncthreads();
#pragma unroll
  for (int nt = 0; nt < 4; ++nt) {
    float sv = 0.f, ssv = 0.f;
#pragma unroll
    for (int w = 0; w < 16; ++w) {
      float2 p2 = part[w * 64 + nt * 16 + c];
      sv += p2.x; ssv += p2.y;
    }
    float m = sv * (1.f / 512.f);
    float rstd = rsqrtf(ssv * (1.f / 512.f) - m * m + 1e-5f);
#pragma unroll
    for (int mt = 0; mt < 2; ++mt)
#pragma unroll
      for (int r = 0; r < 4; ++r)
        acc[mt][nt][r] = (acc[mt][nt][r] - m) * rstd;
  }
#pragma unroll
  for (int mt = 0; mt < 2; ++mt) {
    float4 g4 = *(const float4*)(gamma + wave * 32 + mt * 16 + g * 4);
    float4 be4 = *(const float4*)(beta + wave * 32 + mt * 16 + g * 4);
    int f0 = flb + mt * 16 + g * 4;
#pragma unroll
    for (int nt = 0; nt < 4; ++nt) {
      int T = nt * 16 + c;
      bf16x4 h4;
#pragma unroll
      for (int r = 0; r < 4; ++r) {
        float v = acc[mt][nt][r] * ((const float*)&g4)[r] + ((const float*)&be4)[r];
        h4[r] = (bf16_t)gelu_f(v);
      }
      *(bf16x4*)(dst + SWZ(T, T * 512 + f0 * 2)) = h4;
    }
  }
}

// ========== K_A: x -> GEMM1+LN+GELU -> h(LDS) -> fused G2 -> attn -> ao ==========
__global__ __launch_bounds__(1024, 1) void g1qa_kernel(
    const float* __restrict__ x,
    const bf16_t* __restrict__ w1t, const float* __restrict__ b1,
    const float* __restrict__ gamma1, const float* __restrict__ beta1,
    const bf16_t* __restrict__ w2t, const float* __restrict__ b2,
    const float* __restrict__ bt,
    bf16_t* __restrict__ ao)
{
  __shared__ __align__(16) char sm[163840];
  char* rA = sm;
  char* rB = sm + 32768;
  float2* part = (float2*)(sm + 65536);  // dead before G2 writes qk slots
  const int tid = threadIdx.x;
  const int wave = tid >> 6, lane = tid & 63;
  const int g = lane >> 4, c = lane & 15;
  const int win = blockIdx.x;

  // ---- stage x (f32 -> bf16 tile, coalesced) ----
  const float* xw = x + (size_t)win * 16384;
#pragma unroll
  for (int it = 0; it < 4; ++it) {
    int e = it * 4096 + tid * 4;
    float4 v = *(const float4*)(xw + e);
    int row = e >> 8, col = e & 255;
    bf16x4 t4;
    t4[0] = (bf16_t)v.x; t4[1] = (bf16_t)v.y; t4[2] = (bf16_t)v.z; t4[3] = (bf16_t)v.w;
    *(bf16x4*)(rA + SWZ(row, row * 512 + col * 2)) = t4;
  }
  __syncthreads();
  gemmT_ln_gelu16(rA, w1t, b1, gamma1, beta1, (wave < 8) ? rB : rA, (wave & 7) * 32,
                  part, wave, g, c);
  __syncthreads();  // S1: h complete (rB = feats 0-255, rA = feats 256-511); part dead

  // ---- fused G2: ONE pass over h computes v,q,k (12 MFMA per 4 h-reads);
  //      results go DIRECTLY to their LDS slots (disjoint from h -> no
  //      overlay hazard, no reg-hold, no re-stage phase) ----
  const int hh = wave >> 1, mh = wave & 1;
  {
    f32x4 accv[4] = {}, accq[4] = {}, acck[4] = {};
    const bf16_t* wq = w2t + (size_t)(hh * 32 + mh * 16 + c) * 512;
    const bf16_t* wk = wq + (size_t)256 * 512;
    const bf16_t* wv = wq + (size_t)512 * 512;
#pragma unroll
    for (int kt = 0; kt < 16; ++kt) {
      const char* hb = (kt < 8) ? rB : rA;
      const int ko = (kt & 7) * 64 + g * 16;
      bf16x8 av = *(const bf16x8*)(wv + kt * 32 + g * 8);
      bf16x8 aq = *(const bf16x8*)(wq + kt * 32 + g * 8);
      bf16x8 ak = *(const bf16x8*)(wk + kt * 32 + g * 8);
      bf16x8 b[4];
#pragma unroll
      for (int nt = 0; nt < 4; ++nt) {
        int T = nt * 16 + c;
        b[nt] = *(const bf16x8*)(hb + SWZ(T, T * 512 + ko));
      }
#pragma unroll
      for (int nt = 0; nt < 4; ++nt) {
        accv[nt] = mfma16(av, b[nt], accv[nt]);
        accq[nt] = mfma16(aq, b[nt], accq[nt]);
        acck[nt] = mfma16(ak, b[nt], acck[nt]);
      }
    }
    float4 bv4 = *(const float4*)(b2 + 512 + hh * 32 + mh * 16 + g * 4);
    float4 bq4 = *(const float4*)(b2 + hh * 32 + mh * 16 + g * 4);
    float4 bk4 = *(const float4*)(b2 + 256 + hh * 32 + mh * 16 + g * 4);
    char* qb = sm + 65536 + hh * 8192;
    char* vs = sm + 131072 + hh * 4096;
    const int d0 = mh * 16 + g * 4;
#pragma unroll
    for (int nt = 0; nt < 4; ++nt) {
      int T = nt * 16 + c;
      bf16x4 q4, k4;
#pragma unroll
      for (int r = 0; r < 4; ++r) {
        q4[r] = (bf16_t)((accq[nt][r] + ((const float*)&bq4)[r]) * 0.17677669529663687f);
        k4[r] = (bf16_t)(acck[nt][r] + ((const float*)&bk4)[r]);
      }
      *(bf16x4*)(qb + SWZ(T, T * 64 + d0 * 2)) = q4;
      *(bf16x4*)(qb + 4096 + SWZ(T, T * 64 + d0 * 2)) = k4;
#pragma unroll
      for (int r = 0; r < 4; ++r) {
        int d = d0 + r;
        *(bf16_t*)(vs + SWZ(d, d * 128 + T * 2)) =
            (bf16_t)(accv[nt][r] + ((const float*)&bv4)[r]);
      }
    }
  }
  __syncthreads();  // S2: h reads done AND q/k/vt visible (one barrier)

  // ---- attention: 16 waves = 8 heads x 2 row-halves, single pass ----
  const int h8 = wave & 7, rowbase = (wave >> 3) * 32;
  char* qb = sm + 65536 + h8 * 8192;
  char* vslot = sm + 131072 + h8 * 4096;
  const float* btab = bt + h8 * 4096;  // [64][64] f32

  bf16x8 aq[2], bk[4];
#pragma unroll
  for (int mt = 0; mt < 2; ++mt) {
    int t = rowbase + mt * 16 + c;
    aq[mt] = *(const bf16x8*)(qb + SWZ(t, t * 64 + g * 16));
  }
#pragma unroll
  for (int nt = 0; nt < 4; ++nt) {
    int t = nt * 16 + c;
    bk[nt] = *(const bf16x8*)(qb + 4096 + SWZ(t, t * 64 + g * 16));
  }
  float p[2][4][4];
#pragma unroll
  for (int mt = 0; mt < 2; ++mt)
#pragma unroll
    for (int nt = 0; nt < 4; ++nt) {
      f32x4 z = {0.f, 0.f, 0.f, 0.f};
      f32x4 s4 = mfma16(aq[mt], bk[nt], z);
#pragma unroll
      for (int r = 0; r < 4; ++r) {
        int i = rowbase + mt * 16 + g * 4 + r, j = nt * 16 + c;
        p[mt][nt][r] = s4[r] + btab[i * 64 + j];
      }
    }
#pragma unroll
  for (int mt = 0; mt < 2; ++mt)
#pragma unroll
    for (int r = 0; r < 4; ++r) {
      float mx = fmaxf(fmaxf(p[mt][0][r], p[mt][1][r]), fmaxf(p[mt][2][r], p[mt][3][r]));
#pragma unroll
      for (int m = 1; m < 16; m <<= 1) mx = fmaxf(mx, __shfl_xor(mx, m, 64));
      float sum = 0.f;
#pragma unroll
      for (int nt = 0; nt < 4; ++nt) {
        float e = __expf(p[mt][nt][r] - mx);
        p[mt][nt][r] = e; sum += e;
      }
#pragma unroll
      for (int m = 1; m < 16; m <<= 1) sum += __shfl_xor(sum, m, 64);
      float rinv = 1.f / sum;
#pragma unroll
      for (int nt = 0; nt < 4; ++nt) p[mt][nt][r] *= rinv;
    }
  __syncthreads();  // S3: all q/k reads done before P overlays qk slots

#pragma unroll
  for (int mt = 0; mt < 2; ++mt)
#pragma unroll
    for (int nt = 0; nt < 4; ++nt)
#pragma unroll
      for (int r = 0; r < 4; ++r) {
        int i = rowbase + mt * 16 + g * 4 + r, j = nt * 16 + c;
        *(bf16_t*)(qb + SWZ(i, i * 128 + j * 2)) = (bf16_t)p[mt][nt][r];
      }
  asm volatile("s_waitcnt lgkmcnt(0)" ::: "memory");  // in-wave P write->read (own rows only)
  f32x4 oacc[2][2] = {};
#pragma unroll
  for (int kp = 0; kp < 2; ++kp) {
    bf16x8 ap[2], bv[2];
#pragma unroll
    for (int mt = 0; mt < 2; ++mt) {
      int t = rowbase + mt * 16 + c;
      ap[mt] = *(const bf16x8*)(qb + SWZ(t, t * 128 + kp * 64 + g * 16));
    }
#pragma unroll
    for (int nt = 0; nt < 2; ++nt) {
      int d = nt * 16 + c;
      bv[nt] = *(const bf16x8*)(vslot + SWZ(d, d * 128 + kp * 64 + g * 16));
    }
#pragma unroll
    for (int mt = 0; mt < 2; ++mt)
#pragma unroll
      for (int nt = 0; nt < 2; ++nt)
        oacc[mt][nt] = mfma16(ap[mt], bv[nt], oacc[mt][nt]);
  }
#pragma unroll
  for (int mt = 0; mt < 2; ++mt)
#pragma unroll
    for (int nt = 0; nt < 2; ++nt)
#pragma unroll
      for (int r = 0; r < 4; ++r) {
        int T = rowbase + mt * 16 + g * 4 + r;
        ao[(size_t)(win * 64 + T) * 256 + h8 * 32 + nt * 16 + c] = (bf16_t)oacc[mt][nt][r];
      }
}

// ========== K_B: ao -> GEMM3+LN+GELU -> h2(LDS) -> GEMM4 -> out ==========
__global__ __launch_bounds__(1024, 1) void g3g4_kernel(
    const bf16_t* __restrict__ ao,
    const bf16_t* __restrict__ wp1t, const float* __restrict__ bp1,
    const float* __restrict__ gp, const float* __restrict__ bep,
    const bf16_t* __restrict__ wp2t, const float* __restrict__ bp2,
    float* __restrict__ out)
{
  __shared__ __align__(16) char sm[73728];
  char* rA = sm;
  char* rB = sm + 32768;
  float2* part = (float2*)(sm + 65536);
  const int tid = threadIdx.x;
  const int wave = tid >> 6, lane = tid & 63;
  const int g = lane >> 4, c = lane & 15;
  const int win = blockIdx.x;

  // ---- stage ao (coalesced) ----
  const bf16_t* aow = ao + (size_t)win * 16384;
#pragma unroll
  for (int it = 0; it < 2; ++it) {
    int e = it * 8192 + tid * 8;
    bf16x8 v = *(const bf16x8*)(aow + e);
    int row = e >> 8, col = e & 255;
    *(bf16x8*)(rA + SWZ(row, row * 512 + col * 2)) = v;
  }
  __syncthreads();
  gemmT_ln_gelu16(rA, wp1t, bp1, gp, bep, (wave < 8) ? rB : rA, (wave & 7) * 32,
                  part, wave, g, c);
  __syncthreads();  // h2 complete (rB = feats 0-255, rA = feats 256-511)

  // ---- GEMM4: out = h2 @ wp2 + bp2 (16 waves = 8 feat-32s x 2 token-32s;
  //      halves LDS b-reads vs 16-feat shape) ----
  {
    const int f0 = (wave & 7) * 32, t0 = (wave >> 3) * 32;
    f32x4 acc[2][2] = {};
#pragma unroll
    for (int kt = 0; kt < 16; ++kt) {
      const char* hb = (kt < 8) ? rB : rA;
      const int ko = (kt & 7) * 64 + g * 16;
      bf16x8 a[2], b[2];
#pragma unroll
      for (int mt = 0; mt < 2; ++mt)
        a[mt] = *(const bf16x8*)(wp2t + (size_t)(f0 + mt * 16 + c) * 512 + kt * 32 + g * 8);
#pragma unroll
      for (int nt = 0; nt < 2; ++nt) {
        int T = t0 + nt * 16 + c;
        b[nt] = *(const bf16x8*)(hb + SWZ(T, T * 512 + ko));
      }
#pragma unroll
      for (int mt = 0; mt < 2; ++mt)
#pragma unroll
        for (int nt = 0; nt < 2; ++nt)
          acc[mt][nt] = mfma16(a[mt], b[nt], acc[mt][nt]);
    }
    float* ow = out + (size_t)win * 16384;
#pragma unroll
    for (int mt = 0; mt < 2; ++mt) {
      float4 b4 = *(const float4*)(bp2 + f0 + mt * 16 + g * 4);
#pragma unroll
      for (int nt = 0; nt < 2; ++nt) {
        int T = t0 + nt * 16 + c;
        f32x4 o4;
#pragma unroll
        for (int r = 0; r < 4; ++r) o4[r] = acc[mt][nt][r] + ((const float*)&b4)[r];
        *(f32x4*)(ow + T * 256 + f0 + mt * 16 + g * 4) = o4;
      }
    }
  }
}

extern "C" void kernel_launch(void* const* d_in, const int* in_sizes, int n_in,
                              void* d_out, int out_size, void* d_ws, size_t ws_size,
                              hipStream_t stream) {
  const float* x   = (const float*)d_in[0];
  const float* w1  = (const float*)d_in[1];
  const float* b1  = (const float*)d_in[2];
  const float* g1  = (const float*)d_in[3];
  const float* be1 = (const float*)d_in[4];
  const float* w2  = (const float*)d_in[5];
  const float* b2  = (const float*)d_in[6];
  const float* rpb = (const float*)d_in[7];
  const float* wp1 = (const float*)d_in[8];
  const float* bp1 = (const float*)d_in[9];
  const float* gp  = (const float*)d_in[10];
  const float* bep = (const float*)d_in[11];
  const float* wp2 = (const float*)d_in[12];
  const float* bp2 = (const float*)d_in[13];
  float* out = (float*)d_out;
  char* ws = (char*)d_ws;
  // ws layout: transposed bf16 weights (1.5 MB) | bias table (128 KB) | ao (128 MB)
  bf16_t* w1t  = (bf16_t*)(ws + 0);          // [512][256]
  bf16_t* w2t  = (bf16_t*)(ws + 262144);     // [768][512]
  bf16_t* wp1t = (bf16_t*)(ws + 1048576);    // [512][256]
  bf16_t* wp2t = (bf16_t*)(ws + 1310720);    // [256][512]
  float*  bt   = (float*)(ws + 1572864);     // [8][64][64] f32
  bf16_t* ao   = (bf16_t*)(ws + 2097152);    // [262144][256] bf16 = 128 MB

  prep_kernel<<<3200, 256, 0, stream>>>(w1, w2, wp1, wp2, rpb,
                                        w1t, w2t, wp1t, wp2t, bt);

  g1qa_kernel<<<4096, 1024, 0, stream>>>(x, w1t, b1, g1, be1, w2t, b2, bt, ao);
  g3g4_kernel<<<4096, 1024, 0, stream>>>(ao, wp1t, bp1, gp, bep, wp2t, bp2, out);
}

// Round 9
// 1073.614 us; speedup vs baseline: 1.1590x; 1.1262x over previous
//
#include <hip/hip_runtime.h>

// Two-kernel pipeline, one 64-token window per 1024-thread block (16 waves).
//   K_A: x -> GEMM1+LN+GELU -> h(LDS) -> fused GEMM2(qkv, ONE pass, direct
//        LDS store) -> window attn -> ao (bf16 global)      [round-8, 776 us]
//   K_B: ao -> GEMM3+LN+GELU -> h2(LDS) -> GEMM4 -> out (f32) [round-5 shape]
// Round-8 K_B G4 32x32 reshape regressed ~120us (duplicated weight-row stream
// across wave pairs); reverted to 16 unique out-feats/wave here.
// K_A LDS (160 KB = full CU pool):
//   [0,64K)     rA/rB: x-tile -> h halves
//   [64K,128K)  qk slots, 8 heads x 8K (q | k at +4K); written DIRECTLY by G2;
//               P overlays own head's q|k area during PV. LN partials overlay
//               [64K,72K) during gemmT (dead before G2 writes).
//   [128K,160K) vt 8 heads x 4K, written directly by G2.

typedef __bf16 bf16_t;
typedef __bf16 bf16x8 __attribute__((ext_vector_type(8)));
typedef __bf16 bf16x4 __attribute__((ext_vector_type(4)));
typedef float f32x4 __attribute__((ext_vector_type(4)));

__device__ __forceinline__ f32x4 mfma16(bf16x8 a, bf16x8 b, f32x4 acc) {
  return __builtin_amdgcn_mfma_f32_16x16x32_bf16(a, b, acc, 0, 0, 0);
}

// XOR-swizzle: fold row's low 3 bits into byte-address bits [6:4].
#define SWZ(row, byteoff) ((byteoff) ^ (((row) & 7) << 4))

// cheap GELU: tanh form, max |err| vs exact erf-GELU ~3e-4.
__device__ __forceinline__ float gelu_f(float v) {
  float e = __expf(v * (1.59576912f + 0.07135482f * v * v));
  return v - v * __builtin_amdgcn_rcpf(1.0f + e);
}

// fused prologue: all 4 weight transposes + bias-table expansion in ONE launch.
// segments: w1t[131072] | w2t[393216] | wp1t[131072] | wp2t[131072] | bt[32768]
__global__ void prep_kernel(const float* __restrict__ w1, const float* __restrict__ w2,
                            const float* __restrict__ wp1, const float* __restrict__ wp2,
                            const float* __restrict__ rpb,
                            bf16_t* __restrict__ w1t, bf16_t* __restrict__ w2t,
                            bf16_t* __restrict__ wp1t, bf16_t* __restrict__ wp2t,
                            float* __restrict__ bt) {
  int i = blockIdx.x * 256 + threadIdx.x;
  if (i < 131072) {                    // w1t: [512 feat][256 k], w1 is [256][512]
    int k = i & 255, n = i >> 8;
    w1t[i] = (bf16_t)w1[k * 512 + n];
    return;
  }
  i -= 131072;
  if (i < 393216) {                    // w2t: [768 feat][512 k], w2 is [512][768]
    int k = i & 511, n = i >> 9;
    w2t[i] = (bf16_t)w2[k * 768 + n];
    return;
  }
  i -= 393216;
  if (i < 131072) {                    // wp1t: [512 feat][256 k], wp1 is [256][512]
    int k = i & 255, n = i >> 8;
    wp1t[i] = (bf16_t)wp1[k * 512 + n];
    return;
  }
  i -= 131072;
  if (i < 131072) {                    // wp2t: [256 feat][512 k], wp2 is [512][256]
    int k = i & 511, n = i >> 9;
    wp2t[i] = (bf16_t)wp2[k * 256 + n];
    return;
  }
  i -= 131072;
  if (i < 32768) {                     // bt[8][64][64]
    int hd = i >> 12, r = (i >> 6) & 63, j = i & 63;
    int idx = ((r >> 3) - (j >> 3) + 7) * 15 + ((r & 7) - (j & 7) + 7);
    bt[i] = rpb[idx * 8 + hd];
  }
}

// 16-wave transposed GEMM (C^T = W * A^T) + bias + LayerNorm(512) + cheap GELU.
// Each wave produces 32 output features. bsrc: [64 tok][256 k] bf16 LDS tile
// (swizzled, 512 B rows). wt: [512 feat][256 k] bf16 global.
// Output staged to h-halves in LDS. Contains ONE __syncthreads.
__device__ __forceinline__ void gemmT_ln_gelu16(
    const char* bsrc, const bf16_t* __restrict__ wt,
    const float* __restrict__ bias, const float* __restrict__ gamma,
    const float* __restrict__ beta,
    char* dst, int flb, float2* part, int wave, int g, int c)
{
  f32x4 acc[2][4] = {};
#pragma unroll
  for (int kt = 0; kt < 8; ++kt) {
    bf16x8 a[2], b[4];
#pragma unroll
    for (int mt = 0; mt < 2; ++mt)
      a[mt] = *(const bf16x8*)(wt + (size_t)(wave * 32 + mt * 16 + c) * 256 + kt * 32 + g * 8);
#pragma unroll
    for (int nt = 0; nt < 4; ++nt) {
      int T = nt * 16 + c;
      b[nt] = *(const bf16x8*)(bsrc + SWZ(T, T * 512 + kt * 64 + g * 16));
    }
#pragma unroll
    for (int mt = 0; mt < 2; ++mt)
#pragma unroll
      for (int nt = 0; nt < 4; ++nt)
        acc[mt][nt] = mfma16(a[mt], b[nt], acc[mt][nt]);
  }
  float s[4] = {0.f, 0.f, 0.f, 0.f}, ss[4] = {0.f, 0.f, 0.f, 0.f};
#pragma unroll
  for (int mt = 0; mt < 2; ++mt) {
    float4 b4 = *(const float4*)(bias + wave * 32 + mt * 16 + g * 4);
#pragma unroll
    for (int nt = 0; nt < 4; ++nt)
#pragma unroll
      for (int r = 0; r < 4; ++r) {
        float v = acc[mt][nt][r] + ((const float*)&b4)[r];
        acc[mt][nt][r] = v;
        s[nt] += v;
        ss[nt] += v * v;
      }
  }
#pragma unroll
  for (int nt = 0; nt < 4; ++nt) {
    float sv = s[nt], ssv = ss[nt];
    sv += __shfl_xor(sv, 16, 64); ssv += __shfl_xor(ssv, 16, 64);
    sv += __shfl_xor(sv, 32, 64); ssv += __shfl_xor(ssv, 32, 64);
    if (g == 0) part[wave * 64 + nt * 16 + c] = make_float2(sv, ssv);
  }
  __syncthreads();
#pragma unroll
  for (int nt = 0; nt < 4; ++nt) {
    float sv = 0.f, ssv = 0.f;
#pragma unroll
    for (int w = 0; w < 16; ++w) {
      float2 p2 = part[w * 64 + nt * 16 + c];
      sv += p2.x; ssv += p2.y;
    }
    float m = sv * (1.f / 512.f);
    float rstd = rsqrtf(ssv * (1.f / 512.f) - m * m + 1e-5f);
#pragma unroll
    for (int mt = 0; mt < 2; ++mt)
#pragma unroll
      for (int r = 0; r < 4; ++r)
        acc[mt][nt][r] = (acc[mt][nt][r] - m) * rstd;
  }
#pragma unroll
  for (int mt = 0; mt < 2; ++mt) {
    float4 g4 = *(const float4*)(gamma + wave * 32 + mt * 16 + g * 4);
    float4 be4 = *(const float4*)(beta + wave * 32 + mt * 16 + g * 4);
    int f0 = flb + mt * 16 + g * 4;
#pragma unroll
    for (int nt = 0; nt < 4; ++nt) {
      int T = nt * 16 + c;
      bf16x4 h4;
#pragma unroll
      for (int r = 0; r < 4; ++r) {
        float v = acc[mt][nt][r] * ((const float*)&g4)[r] + ((const float*)&be4)[r];
        h4[r] = (bf16_t)gelu_f(v);
      }
      *(bf16x4*)(dst + SWZ(T, T * 512 + f0 * 2)) = h4;
    }
  }
}

// ========== K_A: x -> GEMM1+LN+GELU -> h(LDS) -> fused G2 -> attn -> ao ==========
__global__ __launch_bounds__(1024, 1) void g1qa_kernel(
    const float* __restrict__ x,
    const bf16_t* __restrict__ w1t, const float* __restrict__ b1,
    const float* __restrict__ gamma1, const float* __restrict__ beta1,
    const bf16_t* __restrict__ w2t, const float* __restrict__ b2,
    const float* __restrict__ bt,
    bf16_t* __restrict__ ao)
{
  __shared__ __align__(16) char sm[163840];
  char* rA = sm;
  char* rB = sm + 32768;
  float2* part = (float2*)(sm + 65536);  // dead before G2 writes qk slots
  const int tid = threadIdx.x;
  const int wave = tid >> 6, lane = tid & 63;
  const int g = lane >> 4, c = lane & 15;
  const int win = blockIdx.x;

  // ---- stage x (f32 -> bf16 tile, coalesced) ----
  const float* xw = x + (size_t)win * 16384;
#pragma unroll
  for (int it = 0; it < 4; ++it) {
    int e = it * 4096 + tid * 4;
    float4 v = *(const float4*)(xw + e);
    int row = e >> 8, col = e & 255;
    bf16x4 t4;
    t4[0] = (bf16_t)v.x; t4[1] = (bf16_t)v.y; t4[2] = (bf16_t)v.z; t4[3] = (bf16_t)v.w;
    *(bf16x4*)(rA + SWZ(row, row * 512 + col * 2)) = t4;
  }
  __syncthreads();
  gemmT_ln_gelu16(rA, w1t, b1, gamma1, beta1, (wave < 8) ? rB : rA, (wave & 7) * 32,
                  part, wave, g, c);
  __syncthreads();  // S1: h complete (rB = feats 0-255, rA = feats 256-511); part dead

  // ---- fused G2: ONE pass over h computes v,q,k (12 MFMA per 4 h-reads);
  //      results go DIRECTLY to their LDS slots (disjoint from h -> no
  //      overlay hazard, no reg-hold, no re-stage phase) ----
  const int hh = wave >> 1, mh = wave & 1;
  {
    f32x4 accv[4] = {}, accq[4] = {}, acck[4] = {};
    const bf16_t* wq = w2t + (size_t)(hh * 32 + mh * 16 + c) * 512;
    const bf16_t* wk = wq + (size_t)256 * 512;
    const bf16_t* wv = wq + (size_t)512 * 512;
#pragma unroll
    for (int kt = 0; kt < 16; ++kt) {
      const char* hb = (kt < 8) ? rB : rA;
      const int ko = (kt & 7) * 64 + g * 16;
      bf16x8 av = *(const bf16x8*)(wv + kt * 32 + g * 8);
      bf16x8 aq = *(const bf16x8*)(wq + kt * 32 + g * 8);
      bf16x8 ak = *(const bf16x8*)(wk + kt * 32 + g * 8);
      bf16x8 b[4];
#pragma unroll
      for (int nt = 0; nt < 4; ++nt) {
        int T = nt * 16 + c;
        b[nt] = *(const bf16x8*)(hb + SWZ(T, T * 512 + ko));
      }
#pragma unroll
      for (int nt = 0; nt < 4; ++nt) {
        accv[nt] = mfma16(av, b[nt], accv[nt]);
        accq[nt] = mfma16(aq, b[nt], accq[nt]);
        acck[nt] = mfma16(ak, b[nt], acck[nt]);
      }
    }
    float4 bv4 = *(const float4*)(b2 + 512 + hh * 32 + mh * 16 + g * 4);
    float4 bq4 = *(const float4*)(b2 + hh * 32 + mh * 16 + g * 4);
    float4 bk4 = *(const float4*)(b2 + 256 + hh * 32 + mh * 16 + g * 4);
    char* qb = sm + 65536 + hh * 8192;
    char* vs = sm + 131072 + hh * 4096;
    const int d0 = mh * 16 + g * 4;
#pragma unroll
    for (int nt = 0; nt < 4; ++nt) {
      int T = nt * 16 + c;
      bf16x4 q4, k4;
#pragma unroll
      for (int r = 0; r < 4; ++r) {
        q4[r] = (bf16_t)((accq[nt][r] + ((const float*)&bq4)[r]) * 0.17677669529663687f);
        k4[r] = (bf16_t)(acck[nt][r] + ((const float*)&bk4)[r]);
      }
      *(bf16x4*)(qb + SWZ(T, T * 64 + d0 * 2)) = q4;
      *(bf16x4*)(qb + 4096 + SWZ(T, T * 64 + d0 * 2)) = k4;
#pragma unroll
      for (int r = 0; r < 4; ++r) {
        int d = d0 + r;
        *(bf16_t*)(vs + SWZ(d, d * 128 + T * 2)) =
            (bf16_t)(accv[nt][r] + ((const float*)&bv4)[r]);
      }
    }
  }
  __syncthreads();  // S2: h reads done AND q/k/vt visible (one barrier)

  // ---- attention: 16 waves = 8 heads x 2 row-halves, single pass ----
  const int h8 = wave & 7, rowbase = (wave >> 3) * 32;
  char* qb = sm + 65536 + h8 * 8192;
  char* vslot = sm + 131072 + h8 * 4096;
  const float* btab = bt + h8 * 4096;  // [64][64] f32

  bf16x8 aq[2], bk[4];
#pragma unroll
  for (int mt = 0; mt < 2; ++mt) {
    int t = rowbase + mt * 16 + c;
    aq[mt] = *(const bf16x8*)(qb + SWZ(t, t * 64 + g * 16));
  }
#pragma unroll
  for (int nt = 0; nt < 4; ++nt) {
    int t = nt * 16 + c;
    bk[nt] = *(const bf16x8*)(qb + 4096 + SWZ(t, t * 64 + g * 16));
  }
  float p[2][4][4];
#pragma unroll
  for (int mt = 0; mt < 2; ++mt)
#pragma unroll
    for (int nt = 0; nt < 4; ++nt) {
      f32x4 z = {0.f, 0.f, 0.f, 0.f};
      f32x4 s4 = mfma16(aq[mt], bk[nt], z);
#pragma unroll
      for (int r = 0; r < 4; ++r) {
        int i = rowbase + mt * 16 + g * 4 + r, j = nt * 16 + c;
        p[mt][nt][r] = s4[r] + btab[i * 64 + j];
      }
    }
#pragma unroll
  for (int mt = 0; mt < 2; ++mt)
#pragma unroll
    for (int r = 0; r < 4; ++r) {
      float mx = fmaxf(fmaxf(p[mt][0][r], p[mt][1][r]), fmaxf(p[mt][2][r], p[mt][3][r]));
#pragma unroll
      for (int m = 1; m < 16; m <<= 1) mx = fmaxf(mx, __shfl_xor(mx, m, 64));
      float sum = 0.f;
#pragma unroll
      for (int nt = 0; nt < 4; ++nt) {
        float e = __expf(p[mt][nt][r] - mx);
        p[mt][nt][r] = e; sum += e;
      }
#pragma unroll
      for (int m = 1; m < 16; m <<= 1) sum += __shfl_xor(sum, m, 64);
      float rinv = 1.f / sum;
#pragma unroll
      for (int nt = 0; nt < 4; ++nt) p[mt][nt][r] *= rinv;
    }
  __syncthreads();  // S3: all q/k reads done before P overlays qk slots

#pragma unroll
  for (int mt = 0; mt < 2; ++mt)
#pragma unroll
    for (int nt = 0; nt < 4; ++nt)
#pragma unroll
      for (int r = 0; r < 4; ++r) {
        int i = rowbase + mt * 16 + g * 4 + r, j = nt * 16 + c;
        *(bf16_t*)(qb + SWZ(i, i * 128 + j * 2)) = (bf16_t)p[mt][nt][r];
      }
  asm volatile("s_waitcnt lgkmcnt(0)" ::: "memory");  // in-wave P write->read (own rows only)
  f32x4 oacc[2][2] = {};
#pragma unroll
  for (int kp = 0; kp < 2; ++kp) {
    bf16x8 ap[2], bv[2];
#pragma unroll
    for (int mt = 0; mt < 2; ++mt) {
      int t = rowbase + mt * 16 + c;
      ap[mt] = *(const bf16x8*)(qb + SWZ(t, t * 128 + kp * 64 + g * 16));
    }
#pragma unroll
    for (int nt = 0; nt < 2; ++nt) {
      int d = nt * 16 + c;
      bv[nt] = *(const bf16x8*)(vslot + SWZ(d, d * 128 + kp * 64 + g * 16));
    }
#pragma unroll
    for (int mt = 0; mt < 2; ++mt)
#pragma unroll
      for (int nt = 0; nt < 2; ++nt)
        oacc[mt][nt] = mfma16(ap[mt], bv[nt], oacc[mt][nt]);
  }
#pragma unroll
  for (int mt = 0; mt < 2; ++mt)
#pragma unroll
    for (int nt = 0; nt < 2; ++nt)
#pragma unroll
      for (int r = 0; r < 4; ++r) {
        int T = rowbase + mt * 16 + g * 4 + r;
        ao[(size_t)(win * 64 + T) * 256 + h8 * 32 + nt * 16 + c] = (bf16_t)oacc[mt][nt][r];
      }
}

// ========== K_B: ao -> GEMM3+LN+GELU -> h2(LDS) -> GEMM4 -> out ==========
__global__ __launch_bounds__(1024, 1) void g3g4_kernel(
    const bf16_t* __restrict__ ao,
    const bf16_t* __restrict__ wp1t, const float* __restrict__ bp1,
    const float* __restrict__ gp, const float* __restrict__ bep,
    const bf16_t* __restrict__ wp2t, const float* __restrict__ bp2,
    float* __restrict__ out)
{
  __shared__ __align__(16) char sm[73728];
  char* rA = sm;
  char* rB = sm + 32768;
  float2* part = (float2*)(sm + 65536);
  const int tid = threadIdx.x;
  const int wave = tid >> 6, lane = tid & 63;
  const int g = lane >> 4, c = lane & 15;
  const int win = blockIdx.x;

  // ---- stage ao (coalesced) ----
  const bf16_t* aow = ao + (size_t)win * 16384;
#pragma unroll
  for (int it = 0; it < 2; ++it) {
    int e = it * 8192 + tid * 8;
    bf16x8 v = *(const bf16x8*)(aow + e);
    int row = e >> 8, col = e & 255;
    *(bf16x8*)(rA + SWZ(row, row * 512 + col * 2)) = v;
  }
  __syncthreads();
  gemmT_ln_gelu16(rA, wp1t, bp1, gp, bep, (wave < 8) ? rB : rA, (wave & 7) * 32,
                  part, wave, g, c);
  __syncthreads();  // h2 complete (rB = feats 0-255, rA = feats 256-511)

  // ---- GEMM4: out = h2 @ wp2 + bp2 (16 waves x 16 unique out-feats;
  //      round-5 shape -- the 32x32 reshape regressed, reverted) ----
  f32x4 acc[4] = {};
#pragma unroll
  for (int kt = 0; kt < 16; ++kt) {
    const char* hb = (kt < 8) ? rB : rA;
    const int ko = (kt & 7) * 64 + g * 16;
    bf16x8 a = *(const bf16x8*)(wp2t + (size_t)(wave * 16 + c) * 512 + kt * 32 + g * 8);
    bf16x8 b[4];
#pragma unroll
    for (int nt = 0; nt < 4; ++nt) {
      int T = nt * 16 + c;
      b[nt] = *(const bf16x8*)(hb + SWZ(T, T * 512 + ko));
    }
#pragma unroll
    for (int nt = 0; nt < 4; ++nt)
      acc[nt] = mfma16(a, b[nt], acc[nt]);
  }
  float* ow = out + (size_t)win * 16384;
  float4 b4 = *(const float4*)(bp2 + wave * 16 + g * 4);
#pragma unroll
  for (int nt = 0; nt < 4; ++nt) {
    int T = nt * 16 + c;
    f32x4 o4;
#pragma unroll
    for (int r = 0; r < 4; ++r) o4[r] = acc[nt][r] + ((const float*)&b4)[r];
    *(f32x4*)(ow + T * 256 + wave * 16 + g * 4) = o4;
  }
}

extern "C" void kernel_launch(void* const* d_in, const int* in_sizes, int n_in,
                              void* d_out, int out_size, void* d_ws, size_t ws_size,
                              hipStream_t stream) {
  const float* x   = (const float*)d_in[0];
  const float* w1  = (const float*)d_in[1];
  const float* b1  = (const float*)d_in[2];
  const float* g1  = (const float*)d_in[3];
  const float* be1 = (const float*)d_in[4];
  const float* w2  = (const float*)d_in[5];
  const float* b2  = (const float*)d_in[6];
  const float* rpb = (const float*)d_in[7];
  const float* wp1 = (const float*)d_in[8];
  const float* bp1 = (const float*)d_in[9];
  const float* gp  = (const float*)d_in[10];
  const float* bep = (const float*)d_in[11];
  const float* wp2 = (const float*)d_in[12];
  const float* bp2 = (const float*)d_in[13];
  float* out = (float*)d_out;
  char* ws = (char*)d_ws;
  // ws layout: transposed bf16 weights (1.5 MB) | bias table (128 KB) | ao (128 MB)
  bf16_t* w1t  = (bf16_t*)(ws + 0);          // [512][256]
  bf16_t* w2t  = (bf16_t*)(ws + 262144);     // [768][512]
  bf16_t* wp1t = (bf16_t*)(ws + 1048576);    // [512][256]
  bf16_t* wp2t = (bf16_t*)(ws + 1310720);    // [256][512]
  float*  bt   = (float*)(ws + 1572864);     // [8][64][64] f32
  bf16_t* ao   = (bf16_t*)(ws + 2097152);    // [262144][256] bf16 = 128 MB

  prep_kernel<<<3200, 256, 0, stream>>>(w1, w2, wp1, wp2, rpb,
                                        w1t, w2t, wp1t, wp2t, bt);

  g1qa_kernel<<<4096, 1024, 0, stream>>>(x, w1t, b1, g1, be1, w2t, b2, bt, ao);
  g3g4_kernel<<<4096, 1024, 0, stream>>>(ao, wp1t, bp1, gp, bep, wp2t, bp2, out);
}